// Round 6
// baseline (120.099 us; speedup 1.0000x reference)
//
#include <hip/hip_runtime.h>
#include <hip/hip_bf16.h>

typedef unsigned int u32;
typedef unsigned long long u64;
typedef __attribute__((ext_vector_type(8))) short bf16x8;
typedef __attribute__((ext_vector_type(4))) float f32x4;
typedef __attribute__((ext_vector_type(4))) u32 u32x4;
typedef __attribute__((ext_vector_type(2))) u32 u32x2;

#define NB 128
#define PP 200
#define KK 60
#define NN (NB*PP)      // 25600
#define HH 64
#define TW 2            // targets per wave
#define NWV 4           // waves per block
#define TB (TW*NWV)     // 8 targets per block
#define BPE (PP/TB)     // 25 blocks per event
#define NTHREADS (NWV*64)

// d_out is FLOAT32. Offsets in f32 elements: out, pos, batch, edge(src,dst)
#define OUT_OFF   0
#define POS_OFF   (NN*HH)             // 1638400
#define BATCH_OFF (POS_OFF + NN*3)    // 1715200
#define ESRC_OFF  (BATCH_OFF + NN)    // 1740800
#define EDST_OFF  (ESRC_OFF + NN*KK)  // 3276800

// truncating bf16x2 pack in ONE v_perm_b32: D = (hi16 of b)<<16 | (hi16 of a)
static __device__ __forceinline__ u32 packtr(float a, float b) {
    return __builtin_amdgcn_perm(__float_as_uint(b), __float_as_uint(a), 0x07060302u);
}
static __device__ __forceinline__ u32 prefix_lt(u64 b) {   // #set bits below lane
    return __builtin_amdgcn_mbcnt_hi((u32)(b >> 32),
                                     __builtin_amdgcn_mbcnt_lo((u32)b, 0));
}
// xor-16 then xor-32 max butterfly entirely on the VALU pipe (no ds_swizzle)
static __device__ __forceinline__ float wavemax16(float v) {
    u32 x = __float_as_uint(v);
    auto p16 = __builtin_amdgcn_permlane16_swap(x, x, false, false);
    float m = fmaxf(__uint_as_float(p16[0]), __uint_as_float(p16[1]));
    u32 y = __float_as_uint(m);
    auto p32 = __builtin_amdgcn_permlane32_swap(y, y, false, false);
    return fmaxf(__uint_as_float(p32[0]), __uint_as_float(p32[1]));
}
// full 64-lane u32 min/max reductions: xor1,2,4,8 via shfl, 16/32 via permlane
static __device__ __forceinline__ u32 wredmin_u32(u32 v) {
    v = min(v, (u32)__shfl_xor((int)v, 1, 64));
    v = min(v, (u32)__shfl_xor((int)v, 2, 64));
    v = min(v, (u32)__shfl_xor((int)v, 4, 64));
    v = min(v, (u32)__shfl_xor((int)v, 8, 64));
    auto p16 = __builtin_amdgcn_permlane16_swap(v, v, false, false);
    v = min((u32)p16[0], (u32)p16[1]);
    auto p32 = __builtin_amdgcn_permlane32_swap(v, v, false, false);
    return min((u32)p32[0], (u32)p32[1]);
}
static __device__ __forceinline__ u32 wredmax_u32(u32 v) {
    v = max(v, (u32)__shfl_xor((int)v, 1, 64));
    v = max(v, (u32)__shfl_xor((int)v, 2, 64));
    v = max(v, (u32)__shfl_xor((int)v, 4, 64));
    v = max(v, (u32)__shfl_xor((int)v, 8, 64));
    auto p16 = __builtin_amdgcn_permlane16_swap(v, v, false, false);
    v = max((u32)p16[0], (u32)p16[1]);
    auto p32 = __builtin_amdgcn_permlane32_swap(v, v, false, false);
    return max((u32)p32[0], (u32)p32[1]);
}

// ---------------------------------------------------------------------------
// R6: VALU-work model (VALUBusy*dur ~ const across R0-R5) says: cut REAL work.
// (1) search reverted to skip-done + per-iter exit (branchless-32 ADDED work),
// (2) search seeded with [wave-min(key), wave-max(key+1)) -- ~5 fewer iters,
// (3) msg LDS eliminated: B-frag lanes 16-63 hit zeros in w1f, so mu = mrow
//     self-permlane rotations in registers (no write->read RAW, -4KB LDS).
// Geometry: best-measured 256thr / 4 waves / TW=2 / grid 3200.
// ---------------------------------------------------------------------------
__global__ __launch_bounds__(NTHREADS) void fused_kernel(const float* __restrict__ x,
                                                    const float* __restrict__ pos,
                                                    const float* __restrict__ W1,
                                                    const float* __restrict__ b1p,
                                                    const float* __restrict__ W2,
                                                    const float* __restrict__ b2p,
                                                    float* __restrict__ out) {
    __shared__ alignas(16) u32 xsp[PP * 2];           // 1600 B  x rows pre-packed bf16x2
    __shared__ alignas(16) float psl[PP * 3];         // 2400 B
    __shared__ alignas(16) u32 jslot[NWV * TW * 64];  // 2048 B
    __shared__ alignas(16) u32 pkW1[64 * 4];          // 1024 B
    __shared__ alignas(16) u32 pkW2T[64 * 33];        // 8448 B (stride 33: conflict-free)
    __shared__ alignas(16) float b2s[64];             // 256 B
    // total = 15,776 B

    int tid = threadIdx.x, blk = blockIdx.x;
    int e = blk / BPE;
    int pl0b = (blk % BPE) * TB;
    int i0b  = e * PP + pl0b;

    // pos/batch passthrough straight from global (no barrier dependency)
    if (tid < 3*TB) out[POS_OFF + i0b * 3 + tid] = pos[i0b * 3 + tid];
    if (tid < TB)   out[BATCH_OFF + i0b + tid] = (float)e;

    if (tid < 200) {                                  // x staged already bf16-packed
        f32x4 xv = ((const f32x4*)x)[e * PP + tid];
        u32x2 p; p[0] = packtr(xv[0], xv[1]); p[1] = packtr(xv[2], xv[3]);
        *(u32x2*)&xsp[tid * 2] = p;
    }
    if (tid < 150) ((f32x4*)psl)[tid] = ((const f32x4*)pos)[e * 150 + tid];

    // ---- block-level packed-weight staging ----
    {   // pkW1: 256 entries: m = tid&63, d = tid>>6
        int m = tid & 63, d = tid >> 6;
        float hiv = (d < 3) ? W1[(2*d + 1)*64 + m] : b1p[m];   // bias in slot 7
        pkW1[m*4 + d] = packtr(W1[(2*d)*64 + m], hiv);
    }
    #pragma unroll
    for (int r = 0; r < 4; ++r) {                 // pkW2T via vectorized f32x4 loads
        int g = r * NTHREADS + tid;               // [0,1024): kp in [0,32), colq in [0,16)
        int kp = g >> 4, colq = g & 15;
        f32x4 ra = *(const f32x4*)&W2[(2*kp)    *64 + colq*4];
        f32x4 rb = *(const f32x4*)&W2[(2*kp + 1)*64 + colq*4];
        #pragma unroll
        for (int c = 0; c < 4; ++c)
            pkW2T[(colq*4 + c)*33 + kp] = packtr(ra[c], rb[c]);
    }
    if (tid < 64) b2s[tid] = b2p[tid];
    __syncthreads();

    int lane = tid & 63, wv = tid >> 6;
    int lo16 = lane & 15, hi16 = lane >> 4;
    int plW0 = pl0b + wv * TW;
    int iW0  = e * PP + plW0;

    // EDST is search-independent: store early
    #pragma unroll
    for (int t = 0; t < TW; ++t)
        if (lane < KK) out[EDST_OFF + (iW0 + t) * KK + lane] = (float)(iW0 + t);

    // ---------------- Phase B: key build for two targets ----------------
    u32 key[TW][4];
    {
        float ax[TW], ay[TW], az[TW];
        #pragma unroll
        for (int t = 0; t < TW; ++t) {
            ax[t] = psl[(plW0+t)*3]; ay[t] = psl[(plW0+t)*3+1]; az[t] = psl[(plW0+t)*3+2];
        }
        #pragma unroll
        for (int q = 0; q < 4; ++q) {
            int j = lane + q * 64;
            int jc = (j < PP) ? j : 0;
            float px = psl[jc*3], py = psl[jc*3+1], pz = psl[jc*3+2];
            #pragma unroll
            for (int t = 0; t < TW; ++t) {
                float dx = px-ax[t], dy = py-ay[t], dz = pz-az[t];
                float d2 = dx*dx + dy*dy + dz*dz;
                key[t][q] = (j < PP && j != plW0 + t)
                          ? ((__float_as_uint(d2) & 0xFFFFFF00u) | (u32)j) : 0xFFFFFFFFu;
            }
        }
    }

    // ---- weight fragment loads issued HERE: the bisection below is mostly
    // ballot/SALU, so these LDS loads complete under the search ----
    bf16x8 w1f[4];
    #pragma unroll
    for (int th = 0; th < 4; ++th) {
        union { u32 w[4]; bf16x8 v; } u;
        if (hi16 == 0) *(u32x4*)u.w = *(const u32x4*)&pkW1[(th * 16 + lo16) * 4];
        else { u.w[0] = u.w[1] = u.w[2] = u.w[3] = 0u; }
        w1f[th] = u.v;
    }
    bf16x8 bfr[4][2];
    #pragma unroll
    for (int t = 0; t < 4; ++t)
        #pragma unroll
        for (int s = 0; s < 2; ++s) {
            union { u32 w[4]; bf16x8 v; } u;
            int base = (t * 16 + lo16) * 33 + s * 16 + hi16 * 4;
            #pragma unroll
            for (int d = 0; d < 4; ++d) u.w[d] = pkW2T[base + d];
            bfr[t][s] = u.v;
        }
    float b2me = b2s[lane];

    // ---------------- seeded, skip-done, early-exit bisection ----------------
    // seeds: lo0 = min(valid keys) (cnt=0<60), hi0 = max(valid keys)+1 (cnt=199>=60).
    // (key+1 maps invalid 0xFFFFFFFF -> 0, masking them from the max for free)
    u32 lo[TW], hi[TW]; int done[TW];
    #pragma unroll
    for (int t = 0; t < TW; ++t) {
        u32 mn = min(min(key[t][0], key[t][1]), min(key[t][2], key[t][3]));
        u32 mx = max(max(key[t][0] + 1u, key[t][1] + 1u),
                     max(key[t][2] + 1u, key[t][3] + 1u));
        lo[t] = wredmin_u32(mn);
        hi[t] = wredmax_u32(mx);
        done[t] = 0;
    }
    #pragma unroll 1
    for (int it = 0; it < 32; ++it) {
        #pragma unroll
        for (int t = 0; t < TW; ++t) {
            if (!done[t]) {
                u32 m = lo[t] + ((hi[t] - lo[t]) >> 1);
                int c = __builtin_popcountll(__ballot(key[t][0] < m))
                      + __builtin_popcountll(__ballot(key[t][1] < m))
                      + __builtin_popcountll(__ballot(key[t][2] < m))
                      + __builtin_popcountll(__ballot(key[t][3] < m));
                if (c >= KK) hi[t] = m; else lo[t] = m;
                done[t] = (c == KK) | (hi[t] - lo[t] <= 1u);
            }
        }
        int alldone = done[0];
        #pragma unroll
        for (int t = 1; t < TW; ++t) alldone &= done[t];
        if (alldone) break;
    }

    // ---------------- compaction -> jslot; coalesced ESRC ----------------
    const int jsb = wv * (TW * 64);
    #pragma unroll
    for (int t = 0; t < TW; ++t) {
        if (lane >= KK) jslot[jsb + t * 64 + lane] = (u32)(plW0 + t);  // self slots
        u64 m0 = __ballot(key[t][0] < hi[t]);
        u64 m1 = __ballot(key[t][1] < hi[t]);
        u64 m2 = __ballot(key[t][2] < hi[t]);
        u64 m3 = __ballot(key[t][3] < hi[t]);
        u32 s1 = (u32)__builtin_popcountll(m0);
        u32 s2 = s1 + (u32)__builtin_popcountll(m1);
        u32 s3 = s2 + (u32)__builtin_popcountll(m2);
        u32 sl[4] = { prefix_lt(m0), s1 + prefix_lt(m1),
                      s2 + prefix_lt(m2), s3 + prefix_lt(m3) };
        #pragma unroll
        for (int q = 0; q < 4; ++q)
            if (key[t][q] < hi[t]) jslot[jsb + t * 64 + (int)sl[q]] = key[t][q] & 0xFFu;
    }
    #pragma unroll
    for (int t = 0; t < TW; ++t) {
        int i = iW0 + t;
        if (lane < KK)
            out[ESRC_OFF + i * KK + lane] = (float)(e * PP + (int)jslot[jsb + t * 64 + lane]);
    }

    // ---------------- Phase C: MLP + max-aggregate (register-resident msg) ----
    for (int tl = 0; tl < TW; ++tl) {
        int i = iW0 + tl, pl = plW0 + tl;
        int jloc = (int)jslot[jsb + tl * 64 + lane];
        u32x2 xp = *(const u32x2*)&xsp[jloc * 2];     // pre-packed bf16 features
        float rx = psl[jloc*3]   - psl[pl*3];
        float ry = psl[jloc*3+1] - psl[pl*3+1];
        float rz = psl[jloc*3+2] - psl[pl*3+2];
        u32 mr[4];
        mr[0] = xp[0];
        mr[1] = xp[1];
        mr[2] = packtr(rx, ry);
        mr[3] = packtr(rz, 1.0f);
        // lane l holds msg row l in mr. The rt-loop B-frag only needs lanes
        // 0-15 to hold row rt*16+lo16; lanes 16-63 multiply w1f's ZEROS, so
        // their (rotated-garbage) contents are harmless.

        float rmax[4] = {-3.0e38f, -3.0e38f, -3.0e38f, -3.0e38f};
        __builtin_amdgcn_s_setprio(1);
        #pragma unroll
        for (int rt = 0; rt < 4; ++rt) {
            union { u32 w[4]; bf16x8 v; } mu;
            #pragma unroll
            for (int d = 0; d < 4; ++d) {
                if (rt == 0) {
                    mu.w[d] = mr[d];
                } else if (rt == 1) {      // lanes0-15 <- lanes16-31
                    auto p = __builtin_amdgcn_permlane16_swap(mr[d], mr[d], false, false);
                    mu.w[d] = p[1];
                } else if (rt == 2) {      // lanes0-15 <- lanes32-47
                    auto p = __builtin_amdgcn_permlane32_swap(mr[d], mr[d], false, false);
                    mu.w[d] = p[1];
                } else {                   // lanes0-15 <- lanes48-63
                    auto p = __builtin_amdgcn_permlane32_swap(mr[d], mr[d], false, false);
                    auto q = __builtin_amdgcn_permlane16_swap(p[1], p[1], false, false);
                    mu.w[d] = q[1];
                }
            }

            f32x4 c1[4];
            #pragma unroll
            for (int th = 0; th < 4; ++th)
                c1[th] = __builtin_amdgcn_mfma_f32_16x16x32_bf16(w1f[th], mu.v,
                                                                 (f32x4)0.f, 0, 0, 0);
            f32x4 acc[4];
            #pragma unroll
            for (int t = 0; t < 4; ++t) acc[t] = (f32x4)0.f;

            #pragma unroll
            for (int s = 0; s < 2; ++s) {
                u32 pe0 = packtr(fmaxf(c1[2*s][0], 0.f), fmaxf(c1[2*s][1], 0.f));
                u32 pe1 = packtr(fmaxf(c1[2*s][2], 0.f), fmaxf(c1[2*s][3], 0.f));
                u32 po0 = packtr(fmaxf(c1[2*s+1][0], 0.f), fmaxf(c1[2*s+1][1], 0.f));
                u32 po1 = packtr(fmaxf(c1[2*s+1][2], 0.f), fmaxf(c1[2*s+1][3], 0.f));
                // register repack (permlane32_swap + permlane16_swap), no LDS
                union { u32 w[4]; bf16x8 v; } u;
                {
                    auto t0 = __builtin_amdgcn_permlane32_swap(pe0, po0, false, false);
                    auto w0 = __builtin_amdgcn_permlane16_swap(t0[0], t0[1], false, false);
                    u.w[0] = w0[0]; u.w[2] = w0[1];
                }
                {
                    auto t1 = __builtin_amdgcn_permlane32_swap(pe1, po1, false, false);
                    auto w1 = __builtin_amdgcn_permlane16_swap(t1[0], t1[1], false, false);
                    u.w[1] = w1[0]; u.w[3] = w1[1];
                }
                #pragma unroll
                for (int t = 0; t < 4; ++t)
                    acc[t] = __builtin_amdgcn_mfma_f32_16x16x32_bf16(u.v, bfr[t][s],
                                                                     acc[t], 0, 0, 0);
            }
            #pragma unroll
            for (int t = 0; t < 4; ++t) {
                rmax[t] = fmaxf(fmaxf(acc[t][0], acc[t][1]), rmax[t]);
                rmax[t] = fmaxf(fmaxf(acc[t][2], acc[t][3]), rmax[t]);
            }
        }
        __builtin_amdgcn_s_setprio(0);
        #pragma unroll
        for (int t = 0; t < 4; ++t) rmax[t] = wavemax16(rmax[t]);
        float sel = rmax[0];
        sel = (hi16 == 1) ? rmax[1] : sel;
        sel = (hi16 == 2) ? rmax[2] : sel;
        sel = (hi16 == 3) ? rmax[3] : sel;
        out[OUT_OFF + i * 64 + lane] = fmaxf(sel + b2me, 0.f);
    }
}

// ---------------------------------------------------------------------------
extern "C" void kernel_launch(void* const* d_in, const int* in_sizes, int n_in,
                              void* d_out, int out_size, void* d_ws, size_t ws_size,
                              hipStream_t stream) {
    const float* x     = (const float*)d_in[0];
    const float* pos   = (const float*)d_in[1];
    const float* W1    = (const float*)d_in[3];
    const float* b1    = (const float*)d_in[4];
    const float* W2    = (const float*)d_in[5];
    const float* b2    = (const float*)d_in[6];
    float* out = (float*)d_out;
    (void)d_ws; (void)ws_size; (void)in_sizes; (void)n_in; (void)out_size;

    fused_kernel<<<dim3(NN / TB), dim3(NTHREADS), 0, stream>>>(x, pos, W1, b1, W2, b2, out);
}

// Round 9
// 117.394 us; speedup vs baseline: 1.0230x; 1.0230x over previous
//
#include <hip/hip_runtime.h>
#include <hip/hip_bf16.h>

typedef unsigned int u32;
typedef unsigned long long u64;
typedef __attribute__((ext_vector_type(8))) short bf16x8;
typedef __attribute__((ext_vector_type(4))) float f32x4;
typedef __attribute__((ext_vector_type(4))) u32 u32x4;
typedef __attribute__((ext_vector_type(2))) u32 u32x2;

#define NB 128
#define PP 200
#define KK 60
#define NN (NB*PP)      // 25600
#define HH 64
#define TW 2            // targets per wave
#define NWV 4           // waves per block
#define TB (TW*NWV)     // 8 targets per tile
#define NTILE 25        // tiles per event
#define TPB 2           // tiles per block (last block of event does 1)
#define BPE 13          // blocks per event: 12x2 + 1x1 = 25 tiles
#define NTHREADS (NWV*64)

// d_out is FLOAT32. Offsets in f32 elements: out, pos, batch, edge(src,dst)
#define OUT_OFF   0
#define POS_OFF   (NN*HH)             // 1638400
#define BATCH_OFF (POS_OFF + NN*3)    // 1715200
#define ESRC_OFF  (BATCH_OFF + NN)    // 1740800
#define EDST_OFF  (ESRC_OFF + NN*KK)  // 3276800

// truncating bf16x2 pack in ONE v_perm_b32: D = (hi16 of b)<<16 | (hi16 of a)
static __device__ __forceinline__ u32 packtr(float a, float b) {
    return __builtin_amdgcn_perm(__float_as_uint(b), __float_as_uint(a), 0x07060302u);
}
static __device__ __forceinline__ u32 prefix_lt(u64 b) {   // #set bits below lane
    return __builtin_amdgcn_mbcnt_hi((u32)(b >> 32),
                                     __builtin_amdgcn_mbcnt_lo((u32)b, 0));
}
// xor-16 then xor-32 max butterfly entirely on the VALU pipe (no ds_swizzle)
static __device__ __forceinline__ float wavemax16(float v) {
    u32 x = __float_as_uint(v);
    auto p16 = __builtin_amdgcn_permlane16_swap(x, x, false, false);
    float m = fmaxf(__uint_as_float(p16[0]), __uint_as_float(p16[1]));
    u32 y = __float_as_uint(m);
    auto p32 = __builtin_amdgcn_permlane32_swap(y, y, false, false);
    return fmaxf(__uint_as_float(p32[0]), __uint_as_float(p32[1]));
}

// ---------------------------------------------------------------------------
// R7 (third attempt; prior two runs failed at container acquire, no kernel
// evidence): persistent-tile restructure. Diagnosis: residency stuck at
// ~2.5 blocks/CU (cap 8) in ALL measured rounds -> launch/drain-dynamics-
// limited, not resource- or instruction-limited. Fix: 1664 blocks, each
// staging its event + weights ONCE then processing 2 consecutive 8-target
// tiles with no inter-tile barrier (per-wave jslot/msg slices). Body =
// best-measured R1/R5 form: skip-done unseeded ballot bisection, msg-in-LDS
// Phase C, weights loaded post-search.
// ---------------------------------------------------------------------------
__global__ __launch_bounds__(NTHREADS) void fused_kernel(const float* __restrict__ x,
                                                    const float* __restrict__ pos,
                                                    const float* __restrict__ W1,
                                                    const float* __restrict__ b1p,
                                                    const float* __restrict__ W2,
                                                    const float* __restrict__ b2p,
                                                    float* __restrict__ out) {
    __shared__ alignas(16) u32 xsp[PP * 2];           // 1600 B  x rows pre-packed bf16x2
    __shared__ alignas(16) float psl[PP * 3];         // 2400 B
    __shared__ alignas(16) u32 jslot[NWV * TW * 64];  // 2048 B (per-wave slice)
    __shared__ alignas(16) u32 msg[NWV * 256];        // 4096 B (per-wave slice)
    __shared__ alignas(16) u32 pkW1[64 * 4];          // 1024 B
    __shared__ alignas(16) u32 pkW2T[64 * 33];        // 8448 B (stride 33: conflict-free)
    __shared__ alignas(16) float b2s[64];             // 256 B
    __shared__ alignas(16) u32 zrow[4];               // 16 B zero B-frag row
    // total = 19,888 B -> 8 blocks/CU LDS cap

    int tid = threadIdx.x, blk = blockIdx.x;
    int e   = blk / BPE;
    int tb0 = (blk % BPE) * TPB;                      // first tile index (0..24)
    int ntile = (tb0 + 1 < NTILE) ? TPB : 1;          // last block of event: 1 tile

    if (tid < 200) {                                  // x staged already bf16-packed
        f32x4 xv = ((const f32x4*)x)[e * PP + tid];
        u32x2 p; p[0] = packtr(xv[0], xv[1]); p[1] = packtr(xv[2], xv[3]);
        *(u32x2*)&xsp[tid * 2] = p;
    }
    if (tid < 150) ((f32x4*)psl)[tid] = ((const f32x4*)pos)[e * 150 + tid];
    if (tid < 4)   zrow[tid] = 0u;

    // ---- block-level packed-weight staging (once per block, 2 tiles) ----
    {   // pkW1: 256 entries: m = tid&63, d = tid>>6
        int m = tid & 63, d = tid >> 6;
        float hiv = (d < 3) ? W1[(2*d + 1)*64 + m] : b1p[m];   // bias in slot 7
        pkW1[m*4 + d] = packtr(W1[(2*d)*64 + m], hiv);
    }
    #pragma unroll
    for (int r = 0; r < 4; ++r) {                 // pkW2T via vectorized f32x4 loads
        int g = r * NTHREADS + tid;               // [0,1024): kp in [0,32), colq in [0,16)
        int kp = g >> 4, colq = g & 15;
        f32x4 ra = *(const f32x4*)&W2[(2*kp)    *64 + colq*4];
        f32x4 rb = *(const f32x4*)&W2[(2*kp + 1)*64 + colq*4];
        #pragma unroll
        for (int c = 0; c < 4; ++c)
            pkW2T[(colq*4 + c)*33 + kp] = packtr(ra[c], rb[c]);
    }
    if (tid < 64) b2s[tid] = b2p[tid];
    __syncthreads();

    int lane = tid & 63, wv = tid >> 6;
    int lo16 = lane & 15, hi16 = lane >> 4;
    float b2me = b2s[lane];
    const int jsb = wv * (TW * 64);
    const int msb = wv * 256;
    const u32* mbase = (hi16 == 0) ? &msg[msb + lo16 * 4] : zrow;
    const int mstep  = (hi16 == 0) ? 64 : 0;

    #pragma unroll 1
    for (int ti = 0; ti < ntile; ++ti) {
        int pl0 = (tb0 + ti) * TB;
        int i0  = e * PP + pl0;

        // pos/batch passthrough for this tile (psl already staged)
        if (tid < 3*TB) out[POS_OFF + i0 * 3 + tid] = psl[pl0 * 3 + tid];
        if (tid < TB)   out[BATCH_OFF + i0 + tid] = (float)e;

        int plW0 = pl0 + wv * TW;
        int iW0  = e * PP + plW0;

        // EDST is search-independent: store early
        #pragma unroll
        for (int t = 0; t < TW; ++t)
            if (lane < KK) out[EDST_OFF + (iW0 + t) * KK + lane] = (float)(iW0 + t);

        // ---------------- Phase B: key build for two targets ----------------
        u32 key[TW][4];
        {
            float ax[TW], ay[TW], az[TW];
            #pragma unroll
            for (int t = 0; t < TW; ++t) {
                ax[t] = psl[(plW0+t)*3]; ay[t] = psl[(plW0+t)*3+1]; az[t] = psl[(plW0+t)*3+2];
            }
            #pragma unroll
            for (int q = 0; q < 4; ++q) {
                int j = lane + q * 64;
                int jc = (j < PP) ? j : 0;
                float px = psl[jc*3], py = psl[jc*3+1], pz = psl[jc*3+2];
                #pragma unroll
                for (int t = 0; t < TW; ++t) {
                    float dx = px-ax[t], dy = py-ay[t], dz = pz-az[t];
                    float d2 = dx*dx + dy*dy + dz*dz;
                    key[t][q] = (j < PP && j != plW0 + t)
                              ? ((__float_as_uint(d2) & 0xFFFFFF00u) | (u32)j) : 0xFFFFFFFFu;
                }
            }
        }

        // skip-done early-exit interleaved ballot bisection (best-measured form)
        u32 lo[TW], hi[TW]; int done[TW];
        #pragma unroll
        for (int t = 0; t < TW; ++t) { lo[t] = 0u; hi[t] = 0x7F800000u; done[t] = 0; }
        #pragma unroll 1
        for (int it = 0; it < 40; ++it) {
            #pragma unroll
            for (int t = 0; t < TW; ++t) {
                if (!done[t]) {
                    u32 m = lo[t] + ((hi[t] - lo[t]) >> 1);
                    int c = __builtin_popcountll(__ballot(key[t][0] < m))
                          + __builtin_popcountll(__ballot(key[t][1] < m))
                          + __builtin_popcountll(__ballot(key[t][2] < m))
                          + __builtin_popcountll(__ballot(key[t][3] < m));
                    if (c >= KK) hi[t] = m; else lo[t] = m;
                    done[t] = (c == KK) | (hi[t] - lo[t] <= 1u);
                }
            }
            int alldone = done[0];
            #pragma unroll
            for (int t = 1; t < TW; ++t) alldone &= done[t];
            if (alldone) break;
        }

        // ---------------- compaction -> jslot; coalesced ESRC ----------------
        #pragma unroll
        for (int t = 0; t < TW; ++t) {
            if (lane >= KK) jslot[jsb + t * 64 + lane] = (u32)(plW0 + t);  // self slots
            u64 m0 = __ballot(key[t][0] < hi[t]);
            u64 m1 = __ballot(key[t][1] < hi[t]);
            u64 m2 = __ballot(key[t][2] < hi[t]);
            u64 m3 = __ballot(key[t][3] < hi[t]);
            u32 s1 = (u32)__builtin_popcountll(m0);
            u32 s2 = s1 + (u32)__builtin_popcountll(m1);
            u32 s3 = s2 + (u32)__builtin_popcountll(m2);
            u32 sl[4] = { prefix_lt(m0), s1 + prefix_lt(m1),
                          s2 + prefix_lt(m2), s3 + prefix_lt(m3) };
            #pragma unroll
            for (int q = 0; q < 4; ++q)
                if (key[t][q] < hi[t]) jslot[jsb + t * 64 + (int)sl[q]] = key[t][q] & 0xFFu;
        }
        #pragma unroll
        for (int t = 0; t < TW; ++t) {
            int i = iW0 + t;
            if (lane < KK)
                out[ESRC_OFF + i * KK + lane] = (float)(e * PP + (int)jslot[jsb + t * 64 + lane]);
        }

        // ---- weight fragment loads (R1 position: keys dead, low VGPR) ----
        bf16x8 w1f[4];
        #pragma unroll
        for (int th = 0; th < 4; ++th) {
            union { u32 w[4]; bf16x8 v; } u;
            if (hi16 == 0) *(u32x4*)u.w = *(const u32x4*)&pkW1[(th * 16 + lo16) * 4];
            else { u.w[0] = u.w[1] = u.w[2] = u.w[3] = 0u; }
            w1f[th] = u.v;
        }
        bf16x8 bfr[4][2];
        #pragma unroll
        for (int t = 0; t < 4; ++t)
            #pragma unroll
            for (int s = 0; s < 2; ++s) {
                union { u32 w[4]; bf16x8 v; } u;
                int base = (t * 16 + lo16) * 33 + s * 16 + hi16 * 4;
                #pragma unroll
                for (int d = 0; d < 4; ++d) u.w[d] = pkW2T[base + d];
                bfr[t][s] = u.v;
            }

        // ---------------- Phase C: MLP + max-aggregate ----------------
        for (int tl = 0; tl < TW; ++tl) {
            int i = iW0 + tl, pl = plW0 + tl;
            int jloc = (int)jslot[jsb + tl * 64 + lane];
            u32x2 xp = *(const u32x2*)&xsp[jloc * 2];     // pre-packed bf16 features
            float rx = psl[jloc*3]   - psl[pl*3];
            float ry = psl[jloc*3+1] - psl[pl*3+1];
            float rz = psl[jloc*3+2] - psl[pl*3+2];
            u32x4 mrow;
            mrow[0] = xp[0];
            mrow[1] = xp[1];
            mrow[2] = packtr(rx, ry);
            mrow[3] = packtr(rz, 1.0f);
            *(u32x4*)&msg[msb + lane * 4] = mrow;

            float rmax[4] = {-3.0e38f, -3.0e38f, -3.0e38f, -3.0e38f};
            __builtin_amdgcn_s_setprio(1);
            #pragma unroll
            for (int rt = 0; rt < 4; ++rt) {
                union { u32 w[4]; bf16x8 v; } mu;
                *(u32x4*)mu.w = *(const u32x4*)(mbase + rt * mstep);

                f32x4 c1[4];
                #pragma unroll
                for (int th = 0; th < 4; ++th)
                    c1[th] = __builtin_amdgcn_mfma_f32_16x16x32_bf16(w1f[th], mu.v,
                                                                     (f32x4)0.f, 0, 0, 0);
                f32x4 acc[4];
                #pragma unroll
                for (int t = 0; t < 4; ++t) acc[t] = (f32x4)0.f;

                #pragma unroll
                for (int s = 0; s < 2; ++s) {
                    u32 pe0 = packtr(fmaxf(c1[2*s][0], 0.f), fmaxf(c1[2*s][1], 0.f));
                    u32 pe1 = packtr(fmaxf(c1[2*s][2], 0.f), fmaxf(c1[2*s][3], 0.f));
                    u32 po0 = packtr(fmaxf(c1[2*s+1][0], 0.f), fmaxf(c1[2*s+1][1], 0.f));
                    u32 po1 = packtr(fmaxf(c1[2*s+1][2], 0.f), fmaxf(c1[2*s+1][3], 0.f));
                    // register repack (permlane32_swap + permlane16_swap), no LDS
                    union { u32 w[4]; bf16x8 v; } u;
                    {
                        auto t0 = __builtin_amdgcn_permlane32_swap(pe0, po0, false, false);
                        auto w0 = __builtin_amdgcn_permlane16_swap(t0[0], t0[1], false, false);
                        u.w[0] = w0[0]; u.w[2] = w0[1];
                    }
                    {
                        auto t1 = __builtin_amdgcn_permlane32_swap(pe1, po1, false, false);
                        auto w1 = __builtin_amdgcn_permlane16_swap(t1[0], t1[1], false, false);
                        u.w[1] = w1[0]; u.w[3] = w1[1];
                    }
                    #pragma unroll
                    for (int t = 0; t < 4; ++t)
                        acc[t] = __builtin_amdgcn_mfma_f32_16x16x32_bf16(u.v, bfr[t][s],
                                                                         acc[t], 0, 0, 0);
                }
                #pragma unroll
                for (int t = 0; t < 4; ++t) {
                    rmax[t] = fmaxf(fmaxf(acc[t][0], acc[t][1]), rmax[t]);
                    rmax[t] = fmaxf(fmaxf(acc[t][2], acc[t][3]), rmax[t]);
                }
            }
            __builtin_amdgcn_s_setprio(0);
            #pragma unroll
            for (int t = 0; t < 4; ++t) rmax[t] = wavemax16(rmax[t]);
            float sel = rmax[0];
            sel = (hi16 == 1) ? rmax[1] : sel;
            sel = (hi16 == 2) ? rmax[2] : sel;
            sel = (hi16 == 3) ? rmax[3] : sel;
            out[OUT_OFF + i * 64 + lane] = fmaxf(sel + b2me, 0.f);
        }
    }
}

// ---------------------------------------------------------------------------
extern "C" void kernel_launch(void* const* d_in, const int* in_sizes, int n_in,
                              void* d_out, int out_size, void* d_ws, size_t ws_size,
                              hipStream_t stream) {
    const float* x     = (const float*)d_in[0];
    const float* pos   = (const float*)d_in[1];
    const float* W1    = (const float*)d_in[3];
    const float* b1    = (const float*)d_in[4];
    const float* W2    = (const float*)d_in[5];
    const float* b2    = (const float*)d_in[6];
    float* out = (float*)d_out;
    (void)d_ws; (void)ws_size; (void)in_sizes; (void)n_in; (void)out_size;

    fused_kernel<<<dim3(NB * BPE), dim3(NTHREADS), 0, stream>>>(x, pos, W1, b1, W2, b2, out);
}

// Round 10
// 110.736 us; speedup vs baseline: 1.0846x; 1.0601x over previous
//
#include <hip/hip_runtime.h>
#include <hip/hip_bf16.h>

typedef unsigned int u32;
typedef unsigned long long u64;
typedef __attribute__((ext_vector_type(8))) short bf16x8;
typedef __attribute__((ext_vector_type(4))) float f32x4;
typedef __attribute__((ext_vector_type(4))) u32 u32x4;
typedef __attribute__((ext_vector_type(2))) u32 u32x2;

#define NB 128
#define PP 200
#define KK 60
#define NN (NB*PP)      // 25600
#define HH 64
#define NWV 4           // waves per block
#define TB NWV          // 4 targets per block (ONE target per wave)
#define BPE (PP/TB)     // 50 blocks per event
#define NTHREADS (NWV*64)

// d_out is FLOAT32. Offsets in f32 elements: out, pos, batch, edge(src,dst)
#define OUT_OFF   0
#define POS_OFF   (NN*HH)             // 1638400
#define BATCH_OFF (POS_OFF + NN*3)    // 1715200
#define ESRC_OFF  (BATCH_OFF + NN)    // 1740800
#define EDST_OFF  (ESRC_OFF + NN*KK)  // 3276800

// truncating bf16x2 pack in ONE v_perm_b32: D = (hi16 of b)<<16 | (hi16 of a)
static __device__ __forceinline__ u32 packtr(float a, float b) {
    return __builtin_amdgcn_perm(__float_as_uint(b), __float_as_uint(a), 0x07060302u);
}
static __device__ __forceinline__ u32 prefix_lt(u64 b) {   // #set bits below lane
    return __builtin_amdgcn_mbcnt_hi((u32)(b >> 32),
                                     __builtin_amdgcn_mbcnt_lo((u32)b, 0));
}
// xor-16 then xor-32 max butterfly entirely on the VALU pipe (no ds_swizzle)
static __device__ __forceinline__ float wavemax16(float v) {
    u32 x = __float_as_uint(v);
    auto p16 = __builtin_amdgcn_permlane16_swap(x, x, false, false);
    float m = fmaxf(__uint_as_float(p16[0]), __uint_as_float(p16[1]));
    u32 y = __float_as_uint(m);
    auto p32 = __builtin_amdgcn_permlane32_swap(y, y, false, false);
    return fmaxf(__uint_as_float(p32[0]), __uint_as_float(p32[1]));
}

// ---------------------------------------------------------------------------
// R9: TW=1 decisive experiment. Evidence R0-R7: only monotone signal is
// "smaller per-wave work, many small 256-thread blocks". TW=1 halves each
// wave's serial chains (single non-interleaved bisection, single Phase-C
// pass) and doubles wave count to 25600 for latency hiding. Two candidate
// models predict OPPOSITE outcomes (conserved-work: slower; overlap: faster)
// -> this round decides. Body = R7's verified code minus persistence, TW=1.
// ---------------------------------------------------------------------------
__global__ __launch_bounds__(NTHREADS) void fused_kernel(const float* __restrict__ x,
                                                    const float* __restrict__ pos,
                                                    const float* __restrict__ W1,
                                                    const float* __restrict__ b1p,
                                                    const float* __restrict__ W2,
                                                    const float* __restrict__ b2p,
                                                    float* __restrict__ out) {
    __shared__ alignas(16) u32 xsp[PP * 2];           // 1600 B  x rows pre-packed bf16x2
    __shared__ alignas(16) float psl[PP * 3];         // 2400 B
    __shared__ alignas(16) u32 jslot[NWV * 64];       // 1024 B (per-wave slice)
    __shared__ alignas(16) u32 msg[NWV * 256];        // 4096 B (per-wave slice)
    __shared__ alignas(16) u32 pkW1[64 * 4];          // 1024 B
    __shared__ alignas(16) u32 pkW2T[64 * 33];        // 8448 B (stride 33: conflict-free)
    __shared__ alignas(16) float b2s[64];             // 256 B
    __shared__ alignas(16) u32 zrow[4];               // 16 B zero B-frag row
    // total = 18,864 B -> 8 blocks/CU LDS cap

    int tid = threadIdx.x, blk = blockIdx.x;
    int e    = blk / BPE;
    int pl0b = (blk % BPE) * TB;
    int i0b  = e * PP + pl0b;

    if (tid < 200) {                                  // x staged already bf16-packed
        f32x4 xv = ((const f32x4*)x)[e * PP + tid];
        u32x2 p; p[0] = packtr(xv[0], xv[1]); p[1] = packtr(xv[2], xv[3]);
        *(u32x2*)&xsp[tid * 2] = p;
    }
    if (tid < 150) ((f32x4*)psl)[tid] = ((const f32x4*)pos)[e * 150 + tid];
    if (tid < 4)   zrow[tid] = 0u;

    // ---- block-level packed-weight staging ----
    {   // pkW1: 256 entries: m = tid&63, d = tid>>6
        int m = tid & 63, d = tid >> 6;
        float hiv = (d < 3) ? W1[(2*d + 1)*64 + m] : b1p[m];   // bias in slot 7
        pkW1[m*4 + d] = packtr(W1[(2*d)*64 + m], hiv);
    }
    #pragma unroll
    for (int r = 0; r < 4; ++r) {                 // pkW2T via vectorized f32x4 loads
        int g = r * NTHREADS + tid;               // [0,1024): kp in [0,32), colq in [0,16)
        int kp = g >> 4, colq = g & 15;
        f32x4 ra = *(const f32x4*)&W2[(2*kp)    *64 + colq*4];
        f32x4 rb = *(const f32x4*)&W2[(2*kp + 1)*64 + colq*4];
        #pragma unroll
        for (int c = 0; c < 4; ++c)
            pkW2T[(colq*4 + c)*33 + kp] = packtr(ra[c], rb[c]);
    }
    if (tid < 64) b2s[tid] = b2p[tid];
    __syncthreads();

    int lane = tid & 63, wv = tid >> 6;
    int lo16 = lane & 15, hi16 = lane >> 4;
    float b2me = b2s[lane];
    const int jsb = wv * 64;
    const int msb = wv * 256;
    const u32* mbase = (hi16 == 0) ? &msg[msb + lo16 * 4] : zrow;
    const int mstep  = (hi16 == 0) ? 64 : 0;

    // pos/batch passthrough (psl staged; 3*TB=12 values)
    if (tid < 3*TB) out[POS_OFF + i0b * 3 + tid] = psl[pl0b * 3 + tid];
    if (tid < TB)   out[BATCH_OFF + i0b + tid] = (float)e;

    int pl = pl0b + wv;                               // this wave's single target
    int i  = e * PP + pl;

    // EDST is search-independent: store early
    if (lane < KK) out[EDST_OFF + i * KK + lane] = (float)i;

    // ---------------- Phase B: key build (one target) ----------------
    u32 key[4];
    {
        float ax = psl[pl*3], ay = psl[pl*3+1], az = psl[pl*3+2];
        #pragma unroll
        for (int q = 0; q < 4; ++q) {
            int j = lane + q * 64;
            int jc = (j < PP) ? j : 0;
            float px = psl[jc*3], py = psl[jc*3+1], pz = psl[jc*3+2];
            float dx = px-ax, dy = py-ay, dz = pz-az;
            float d2 = dx*dx + dy*dy + dz*dz;
            key[q] = (j < PP && j != pl)
                   ? ((__float_as_uint(d2) & 0xFFFFFF00u) | (u32)j) : 0xFFFFFFFFu;
        }
    }

    // ---- weight fragment loads issued HERE: the bisection below is mostly
    // ballot/SALU, so these LDS loads complete under the search ----
    bf16x8 w1f[4];
    #pragma unroll
    for (int th = 0; th < 4; ++th) {
        union { u32 w[4]; bf16x8 v; } u;
        if (hi16 == 0) *(u32x4*)u.w = *(const u32x4*)&pkW1[(th * 16 + lo16) * 4];
        else { u.w[0] = u.w[1] = u.w[2] = u.w[3] = 0u; }
        w1f[th] = u.v;
    }
    bf16x8 bfr[4][2];
    #pragma unroll
    for (int t = 0; t < 4; ++t)
        #pragma unroll
        for (int s = 0; s < 2; ++s) {
            union { u32 w[4]; bf16x8 v; } u;
            int base = (t * 16 + lo16) * 33 + s * 16 + hi16 * 4;
            #pragma unroll
            for (int d = 0; d < 4; ++d) u.w[d] = pkW2T[base + d];
            bfr[t][s] = u.v;
        }

    // -------- single-target early-exit ballot bisection --------
    // invariant: cnt(lo) < 60 <= cnt(hi); exit on cnt==60 or width<=1
    // (keys unique => width 1 implies cnt(hi)==60)
    u32 lo = 0u, hi = 0x7F800000u;
    #pragma unroll 1
    for (int it = 0; it < 40; ++it) {
        u32 m = lo + ((hi - lo) >> 1);
        int c = __builtin_popcountll(__ballot(key[0] < m))
              + __builtin_popcountll(__ballot(key[1] < m))
              + __builtin_popcountll(__ballot(key[2] < m))
              + __builtin_popcountll(__ballot(key[3] < m));
        if (c >= KK) hi = m; else lo = m;
        if ((c == KK) | (hi - lo <= 1u)) break;
    }

    // ---------------- compaction -> jslot; coalesced ESRC ----------------
    if (lane >= KK) jslot[jsb + lane] = (u32)pl;      // self slots 60..63
    {
        u64 m0 = __ballot(key[0] < hi);
        u64 m1 = __ballot(key[1] < hi);
        u64 m2 = __ballot(key[2] < hi);
        u64 m3 = __ballot(key[3] < hi);
        u32 s1 = (u32)__builtin_popcountll(m0);
        u32 s2 = s1 + (u32)__builtin_popcountll(m1);
        u32 s3 = s2 + (u32)__builtin_popcountll(m2);
        u32 sl[4] = { prefix_lt(m0), s1 + prefix_lt(m1),
                      s2 + prefix_lt(m2), s3 + prefix_lt(m3) };
        #pragma unroll
        for (int q = 0; q < 4; ++q)
            if (key[q] < hi) jslot[jsb + (int)sl[q]] = key[q] & 0xFFu;
    }
    if (lane < KK)
        out[ESRC_OFF + i * KK + lane] = (float)(e * PP + (int)jslot[jsb + lane]);

    // ---------------- Phase C: MLP + max-aggregate (one target) ----------------
    {
        int jloc = (int)jslot[jsb + lane];
        u32x2 xp = *(const u32x2*)&xsp[jloc * 2];     // pre-packed bf16 features
        float rx = psl[jloc*3]   - psl[pl*3];
        float ry = psl[jloc*3+1] - psl[pl*3+1];
        float rz = psl[jloc*3+2] - psl[pl*3+2];
        u32x4 mrow;
        mrow[0] = xp[0];
        mrow[1] = xp[1];
        mrow[2] = packtr(rx, ry);
        mrow[3] = packtr(rz, 1.0f);
        *(u32x4*)&msg[msb + lane * 4] = mrow;

        float rmax[4] = {-3.0e38f, -3.0e38f, -3.0e38f, -3.0e38f};
        __builtin_amdgcn_s_setprio(1);
        #pragma unroll
        for (int rt = 0; rt < 4; ++rt) {
            union { u32 w[4]; bf16x8 v; } mu;
            *(u32x4*)mu.w = *(const u32x4*)(mbase + rt * mstep);

            f32x4 c1[4];
            #pragma unroll
            for (int th = 0; th < 4; ++th)
                c1[th] = __builtin_amdgcn_mfma_f32_16x16x32_bf16(w1f[th], mu.v,
                                                                 (f32x4)0.f, 0, 0, 0);
            f32x4 acc[4];
            #pragma unroll
            for (int t = 0; t < 4; ++t) acc[t] = (f32x4)0.f;

            #pragma unroll
            for (int s = 0; s < 2; ++s) {
                u32 pe0 = packtr(fmaxf(c1[2*s][0], 0.f), fmaxf(c1[2*s][1], 0.f));
                u32 pe1 = packtr(fmaxf(c1[2*s][2], 0.f), fmaxf(c1[2*s][3], 0.f));
                u32 po0 = packtr(fmaxf(c1[2*s+1][0], 0.f), fmaxf(c1[2*s+1][1], 0.f));
                u32 po1 = packtr(fmaxf(c1[2*s+1][2], 0.f), fmaxf(c1[2*s+1][3], 0.f));
                // register repack (permlane32_swap + permlane16_swap), no LDS
                union { u32 w[4]; bf16x8 v; } u;
                {
                    auto t0 = __builtin_amdgcn_permlane32_swap(pe0, po0, false, false);
                    auto w0 = __builtin_amdgcn_permlane16_swap(t0[0], t0[1], false, false);
                    u.w[0] = w0[0]; u.w[2] = w0[1];
                }
                {
                    auto t1 = __builtin_amdgcn_permlane32_swap(pe1, po1, false, false);
                    auto w1 = __builtin_amdgcn_permlane16_swap(t1[0], t1[1], false, false);
                    u.w[1] = w1[0]; u.w[3] = w1[1];
                }
                #pragma unroll
                for (int t = 0; t < 4; ++t)
                    acc[t] = __builtin_amdgcn_mfma_f32_16x16x32_bf16(u.v, bfr[t][s],
                                                                     acc[t], 0, 0, 0);
            }
            #pragma unroll
            for (int t = 0; t < 4; ++t) {
                rmax[t] = fmaxf(fmaxf(acc[t][0], acc[t][1]), rmax[t]);
                rmax[t] = fmaxf(fmaxf(acc[t][2], acc[t][3]), rmax[t]);
            }
        }
        __builtin_amdgcn_s_setprio(0);
        #pragma unroll
        for (int t = 0; t < 4; ++t) rmax[t] = wavemax16(rmax[t]);
        float sel = rmax[0];
        sel = (hi16 == 1) ? rmax[1] : sel;
        sel = (hi16 == 2) ? rmax[2] : sel;
        sel = (hi16 == 3) ? rmax[3] : sel;
        out[OUT_OFF + i * 64 + lane] = fmaxf(sel + b2me, 0.f);
    }
}

// ---------------------------------------------------------------------------
extern "C" void kernel_launch(void* const* d_in, const int* in_sizes, int n_in,
                              void* d_out, int out_size, void* d_ws, size_t ws_size,
                              hipStream_t stream) {
    const float* x     = (const float*)d_in[0];
    const float* pos   = (const float*)d_in[1];
    const float* W1    = (const float*)d_in[3];
    const float* b1    = (const float*)d_in[4];
    const float* W2    = (const float*)d_in[5];
    const float* b2    = (const float*)d_in[6];
    float* out = (float*)d_out;
    (void)d_ws; (void)ws_size; (void)in_sizes; (void)n_in; (void)out_size;

    fused_kernel<<<dim3(NN / TB), dim3(NTHREADS), 0, stream>>>(x, pos, W1, b1, W2, b2, out);
}

// Round 11
// 109.128 us; speedup vs baseline: 1.1005x; 1.0147x over previous
//
#include <hip/hip_runtime.h>
#include <hip/hip_bf16.h>

typedef unsigned short ushort_t;
typedef unsigned int u32;
typedef unsigned long long u64;
typedef __attribute__((ext_vector_type(8))) short bf16x8;
typedef __attribute__((ext_vector_type(4))) float f32x4;
typedef __attribute__((ext_vector_type(4))) u32 u32x4;

#define NB 128
#define PP 200
#define KK 60
#define NN (NB*PP)      // 25600
#define HH 64

// d_out is FLOAT32. Offsets in f32 elements: out, pos, batch, edge(src,dst)
#define OUT_OFF   0
#define POS_OFF   (NN*HH)             // 1638400
#define BATCH_OFF (POS_OFF + NN*3)    // 1715200
#define ESRC_OFF  (BATCH_OFF + NN)    // 1740800
#define EDST_OFF  (ESRC_OFF + NN*KK)  // 3276800

// truncating bf16x2 pack in ONE v_perm_b32: D = (hi16 of b)<<16 | (hi16 of a)
static __device__ __forceinline__ u32 packtr(float a, float b) {
    return __builtin_amdgcn_perm(__float_as_uint(b), __float_as_uint(a), 0x07060302u);
}
static __device__ __forceinline__ u32 prefix_lt(u64 b) {   // #set bits below lane
    return __builtin_amdgcn_mbcnt_hi((u32)(b >> 32),
                                     __builtin_amdgcn_mbcnt_lo((u32)b, 0));
}

// ---------------------------------------------------------------------------
// FUSED kernel: block = 8 consecutive targets of one event; wave = 2 targets.
// Phase A: stage event x/pos to LDS; pos/batch passthrough.
// Phase B: per-wave keys for 2 targets, interleaved EARLY-EXIT wave-ballot
//   binary searches for the exact-60 threshold, ballot+mbcnt compaction ->
//   ESRC + EDST (final) + jslot LDS (slots 60..63 = self).
// Phase C: all-lane message build (self rows rel=0 naturally), trunc-packed
//   weights, layer-1 MFMA (A = W1'^T, b1 in slot 7) -> conflict-free af
//   permute (single 1KB/wave buffer, s-split) -> layer-2 MFMA; raw-acc max
//   (b2+relu deferred past the max: both commute with it).
//
// Session-final (R10): best-measured source of the session (R0 = 108.56 us
// bench / 49.1 us dispatch). Nine structural perturbations (TW in {1,2,5},
// waves/block {4,5}, persistent tiles, branchless/seeded search, register-
// rotated msg, hoisted weights) all measured 49-68 us dispatch; none beat
// this form. Floor is the fused family's serial-chain x residency product,
// not a HW roofline (HBM 5.5%, MfmaUtil 15%, VALUBusy 55%).
// ---------------------------------------------------------------------------
__global__ __launch_bounds__(256) void fused_kernel(const float* __restrict__ x,
                                                    const float* __restrict__ pos,
                                                    const float* __restrict__ W1,
                                                    const float* __restrict__ b1p,
                                                    const float* __restrict__ W2,
                                                    const float* __restrict__ b2p,
                                                    float* __restrict__ out) {
    __shared__ alignas(16) float xs[PP * 4];     // 3200 B
    __shared__ alignas(16) float psl[PP * 3];    // 2400 B
    __shared__ alignas(16) u32 jslot[4 * 128];   // 2048 B
    __shared__ alignas(16) u32 msg[4 * 256];     // 4096 B
    __shared__ alignas(16) u32 af[4 * 256];      // 4096 B (s-split, 1KB/wave)
    __shared__ alignas(16) u32 zrow[4];          // 16 B zero B-frag row

    int tid = threadIdx.x, blk = blockIdx.x;
    int e = blk / 25;
    int pl0b = (blk % 25) * 8;
    int i0b  = e * PP + pl0b;

    if (tid < 200) ((f32x4*)xs)[tid]  = ((const f32x4*)x)[e * PP + tid];
    if (tid < 150) ((f32x4*)psl)[tid] = ((const f32x4*)pos)[e * 150 + tid];
    if (tid < 4)   zrow[tid] = 0u;
    __syncthreads();

    if (tid < 24) out[POS_OFF + i0b * 3 + tid] = psl[pl0b * 3 + tid];
    if (tid < 8)  out[BATCH_OFF + i0b + tid] = (float)e;

    int lane = tid & 63, wv = tid >> 6;
    int lo16 = lane & 15, hi16 = lane >> 4;
    int plA = pl0b + wv * 2, plB = plA + 1;
    int iA = e * PP + plA,   iB = iA + 1;

    // ---------------- Phase B: KNN for two targets ----------------
    float axA = psl[plA*3], ayA = psl[plA*3+1], azA = psl[plA*3+2];
    float axB = psl[plB*3], ayB = psl[plB*3+1], azB = psl[plB*3+2];

    u32 keyA[4], keyB[4];
    #pragma unroll
    for (int q = 0; q < 4; ++q) {
        int j = lane + q * 64;
        int jc = (j < PP) ? j : 0;
        float px = psl[jc*3], py = psl[jc*3+1], pz = psl[jc*3+2];
        float dxA = px-axA, dyA = py-ayA, dzA = pz-azA;
        float dxB = px-axB, dyB = py-ayB, dzB = pz-azB;
        float d2A = dxA*dxA + dyA*dyA + dzA*dzA;
        float d2B = dxB*dxB + dyB*dyB + dzB*dzB;
        keyA[q] = (j < PP && j != plA)
                ? ((__float_as_uint(d2A) & 0xFFFFFF00u) | (u32)j) : 0xFFFFFFFFu;
        keyB[q] = (j < PP && j != plB)
                ? ((__float_as_uint(d2B) & 0xFFFFFF00u) | (u32)j) : 0xFFFFFFFFu;
    }

    // early-exit interleaved searches: exit a target when cnt == 60 exactly
    // (or interval width 1 => cnt(hi) == 60 since keys unique). d2 finite =>
    // starting hi = inf-bits has cnt = 199 >= 60; invalid keys excluded.
    u32 loA = 0u, hiA = 0x7F800000u, loB = 0u, hiB = 0x7F800000u;
    int doneA = 0, doneB = 0;
    for (int it = 0; it < 32; ++it) {
        u32 mA = loA + ((hiA - loA) >> 1);
        u32 mB = loB + ((hiB - loB) >> 1);
        int cA = __builtin_popcountll(__ballot(keyA[0] < mA))
               + __builtin_popcountll(__ballot(keyA[1] < mA))
               + __builtin_popcountll(__ballot(keyA[2] < mA))
               + __builtin_popcountll(__ballot(keyA[3] < mA));
        int cB = __builtin_popcountll(__ballot(keyB[0] < mB))
               + __builtin_popcountll(__ballot(keyB[1] < mB))
               + __builtin_popcountll(__ballot(keyB[2] < mB))
               + __builtin_popcountll(__ballot(keyB[3] < mB));
        if (!doneA) {
            if (cA >= KK) hiA = mA; else loA = mA;
            doneA = (cA == KK) | (hiA - loA <= 1u);
        }
        if (!doneB) {
            if (cB >= KK) hiB = mB; else loB = mB;
            doneB = (cB == KK) | (hiB - loB <= 1u);
        }
        if (doneA & doneB) break;
    }

    const int jsb = wv * 128;
    if (lane >= KK) {                            // slots 60..63 = self id
        jslot[jsb + lane]      = (u32)plA;
        jslot[jsb + 64 + lane] = (u32)plB;
    }
    #pragma unroll
    for (int t = 0; t < 2; ++t) {
        const u32* key = t ? keyB : keyA;
        u32 hh = t ? hiB : hiA;
        int i  = t ? iB : iA;
        u64 m0 = __ballot(key[0] < hh);
        u64 m1 = __ballot(key[1] < hh);
        u64 m2 = __ballot(key[2] < hh);
        u64 m3 = __ballot(key[3] < hh);
        u32 s1 = (u32)__builtin_popcountll(m0);
        u32 s2 = s1 + (u32)__builtin_popcountll(m1);
        u32 s3 = s2 + (u32)__builtin_popcountll(m2);
        u32 sl[4] = { prefix_lt(m0), s1 + prefix_lt(m1),
                      s2 + prefix_lt(m2), s3 + prefix_lt(m3) };
        #pragma unroll
        for (int q = 0; q < 4; ++q) {
            if (key[q] < hh) {
                u32 j = key[q] & 0xFFu;
                out[ESRC_OFF + i * KK + (int)sl[q]] = (float)(e * PP + (int)j);
                jslot[jsb + t * 64 + (int)sl[q]] = j;
            }
        }
        if (lane < KK) out[EDST_OFF + i * KK + lane] = (float)i;
    }

    // ---------------- weights into registers (trunc-packed) ----------------
    bf16x8 w1f[4];
    #pragma unroll
    for (int th = 0; th < 4; ++th) {
        union { u32 w[4]; bf16x8 v; } u; u.w[0]=u.w[1]=u.w[2]=u.w[3]=0u;
        if (hi16 == 0) {
            int m = th * 16 + lo16;
            u.w[0] = packtr(W1[0*64+m], W1[1*64+m]);
            u.w[1] = packtr(W1[2*64+m], W1[3*64+m]);
            u.w[2] = packtr(W1[4*64+m], W1[5*64+m]);
            u.w[3] = packtr(W1[6*64+m], b1p[m]);     // bias in slot 7
        }
        w1f[th] = u.v;
    }
    bf16x8 bfr[4][2];
    #pragma unroll
    for (int t = 0; t < 4; ++t)
        #pragma unroll
        for (int s = 0; s < 2; ++s) {
            union { u32 w[4]; bf16x8 v; } u;
            int col = t * 16 + lo16, kb = s * 32 + hi16 * 8;
            #pragma unroll
            for (int d = 0; d < 4; ++d)
                u.w[d] = packtr(W2[(kb + 2*d) * 64 + col], W2[(kb + 2*d + 1) * 64 + col]);
            bfr[t][s] = u.v;
        }
    float b2v[4];
    #pragma unroll
    for (int t = 0; t < 4; ++t) b2v[t] = b2p[t * 16 + lo16];

    // ---------------- Phase C: MLP + max-aggregate ----------------
    const int msb = wv * 256;
    const int afb = wv * 256;
    for (int tl = 0; tl < 2; ++tl) {
        int i = iA + tl, pl = plA + tl;
        int jloc = (int)jslot[jsb + tl * 64 + lane];
        f32x4 xv = ((const f32x4*)xs)[jloc];
        float rx = psl[jloc*3]   - psl[pl*3];
        float ry = psl[jloc*3+1] - psl[pl*3+1];
        float rz = psl[jloc*3+2] - psl[pl*3+2];
        u32x4 mrow;
        mrow[0] = packtr(xv[0], xv[1]);
        mrow[1] = packtr(xv[2], xv[3]);
        mrow[2] = packtr(rx, ry);
        mrow[3] = packtr(rz, 1.0f);
        *(u32x4*)&msg[msb + lane * 4] = mrow;

        float rmax[4] = {-3.0e38f, -3.0e38f, -3.0e38f, -3.0e38f};
        #pragma unroll
        for (int rt = 0; rt < 4; ++rt) {
            // B-frag: hi16==0 lanes read their msg row, others a zero row
            const u32* mp = (hi16 == 0) ? &msg[msb + (rt * 16 + lo16) * 4] : zrow;
            union { u32 w[4]; bf16x8 v; } mu;
            *(u32x4*)mu.w = *(const u32x4*)mp;

            f32x4 c1[4];
            #pragma unroll
            for (int th = 0; th < 4; ++th)
                c1[th] = __builtin_amdgcn_mfma_f32_16x16x32_bf16(w1f[th], mu.v,
                                                                 (f32x4)0.f, 0, 0, 0);
            f32x4 acc[4];
            #pragma unroll
            for (int t = 0; t < 4; ++t) acc[t] = (f32x4)0.f;

            #pragma unroll
            for (int s = 0; s < 2; ++s) {        // s-split through one af buffer
                #pragma unroll
                for (int thh = 0; thh < 2; ++thh) {
                    int th = s * 2 + thh;
                    u32 pk0 = packtr(fmaxf(c1[th][0], 0.f), fmaxf(c1[th][1], 0.f));
                    u32 pk1 = packtr(fmaxf(c1[th][2], 0.f), fmaxf(c1[th][3], 0.f));
                    int dlane = lo16 + ((thh * 2 + (hi16 >> 1)) << 4);
                    int dbase = (hi16 & 1) * 2;
                    af[afb + (dbase + 0) * 64 + dlane] = pk0;   // 2-way, free
                    af[afb + (dbase + 1) * 64 + dlane] = pk1;
                }
                union { u32 w[4]; bf16x8 v; } u;
                #pragma unroll
                for (int d = 0; d < 4; ++d)
                    u.w[d] = af[afb + d * 64 + lane];            // in-order LDS
                #pragma unroll
                for (int t = 0; t < 4; ++t)
                    acc[t] = __builtin_amdgcn_mfma_f32_16x16x32_bf16(u.v, bfr[t][s],
                                                                     acc[t], 0, 0, 0);
            }
            // raw-acc max; +b2 and relu commute past the row-max
            #pragma unroll
            for (int t = 0; t < 4; ++t) {
                rmax[t] = fmaxf(fmaxf(acc[t][0], acc[t][1]), rmax[t]);
                rmax[t] = fmaxf(fmaxf(acc[t][2], acc[t][3]), rmax[t]);
            }
        }
        #pragma unroll
        for (int t = 0; t < 4; ++t) {
            rmax[t] = fmaxf(rmax[t], __shfl_xor(rmax[t], 16, 64));
            rmax[t] = fmaxf(rmax[t], __shfl_xor(rmax[t], 32, 64));
        }
        if (lane < 16) {
            #pragma unroll
            for (int t = 0; t < 4; ++t)
                out[OUT_OFF + i * 64 + t * 16 + lane] = fmaxf(rmax[t] + b2v[t], 0.f);
        }
    }
}

// ---------------------------------------------------------------------------
extern "C" void kernel_launch(void* const* d_in, const int* in_sizes, int n_in,
                              void* d_out, int out_size, void* d_ws, size_t ws_size,
                              hipStream_t stream) {
    const float* x     = (const float*)d_in[0];
    const float* pos   = (const float*)d_in[1];
    const float* W1    = (const float*)d_in[3];
    const float* b1    = (const float*)d_in[4];
    const float* W2    = (const float*)d_in[5];
    const float* b2    = (const float*)d_in[6];
    float* out = (float*)d_out;
    (void)d_ws; (void)ws_size; (void)in_sizes; (void)n_in; (void)out_size;

    fused_kernel<<<dim3(NN / 8), dim3(256), 0, stream>>>(x, pos, W1, b1, W2, b2, out);
}